// Round 1
// baseline (343.092 us; speedup 1.0000x reference)
//
#include <hip/hip_runtime.h>
#include <hip/hip_bf16.h>

#define IN_DIM 98304

typedef short bh8 __attribute__((ext_vector_type(8)));
typedef float f32x4 __attribute__((ext_vector_type(4)));
typedef unsigned short u16x8 __attribute__((ext_vector_type(8)));

__device__ __forceinline__ unsigned short f2bf(float f) {
  __hip_bfloat16 h = __float2bfloat16(f);
  return __builtin_bit_cast(unsigned short, h);
}

// ---------------------------------------------------------------------------
// Kernel 1: per-(image,channel) 2D FFT 128x128 + fftshift + amp/phase -> bf16
// One block per (c,b). Whole tile lives in LDS as interleaved float2 (128KB).
// Radix-2 DIT, bit-reversed load (rows) / row-swap (cols), twiddle table.
// ---------------------------------------------------------------------------
__global__ __launch_bounds__(256) void fft_feats_kernel(
    const float* __restrict__ img, unsigned short* __restrict__ feats) {
  __shared__ float2 sm[128 * 128];
  __shared__ float2 tw[64];
  const int tid = threadIdx.x;
  const int c = blockIdx.x, b = blockIdx.y;
  const float* src = img + ((size_t)(b * 3 + c) << 14);

  if (tid < 64) {
    float ang = -3.14159265358979323846f * (float)tid / 64.0f;
    float sv, cv;
    sincosf(ang, &sv, &cv);
    tw[tid] = make_float2(cv, sv);
  }

  // load with bit-reversed w index (prepare for in-place DIT along w)
  for (int i = tid; i < 16384; i += 256) {
    int h = i >> 7, w = i & 127;
    int rw = __brev(w) >> 25;
    sm[(h << 7) | rw] = make_float2(src[i], 0.0f);
  }
  __syncthreads();

  // row FFTs (along w)
  for (int s = 0; s < 7; ++s) {
    int half = 1 << s;
    for (int it = 0; it < 32; ++it) {
      int t = it * 256 + tid;
      int row = t >> 6, jj = t & 63;
      int j = jj & (half - 1);
      int idx0 = ((jj >> s) << (s + 1)) | j;
      int p0 = (row << 7) | idx0;
      int p1 = p0 + half;
      float2 W = tw[j << (6 - s)];
      float2 x0 = sm[p0], x1 = sm[p1];
      float tr = W.x * x1.x - W.y * x1.y;
      float ti = W.x * x1.y + W.y * x1.x;
      sm[p0] = make_float2(x0.x + tr, x0.y + ti);
      sm[p1] = make_float2(x0.x - tr, x0.y - ti);
    }
    __syncthreads();
  }

  // bit-reverse rows (prepare for in-place DIT along h)
  for (int i = tid; i < 16384; i += 256) {
    int h = i >> 7, w = i & 127;
    int rh = __brev(h) >> 25;
    if (rh > h) {
      float2 a = sm[(h << 7) | w];
      float2 bb = sm[(rh << 7) | w];
      sm[(h << 7) | w] = bb;
      sm[(rh << 7) | w] = a;
    }
  }
  __syncthreads();

  // column FFTs (along h)
  for (int s = 0; s < 7; ++s) {
    int half = 1 << s;
    for (int it = 0; it < 32; ++it) {
      int t = it * 256 + tid;
      int col = t & 127, jb = t >> 7;
      int j = jb & (half - 1);
      int idx0 = ((jb >> s) << (s + 1)) | j;
      int p0 = (idx0 << 7) | col;
      int p1 = p0 + (half << 7);
      float2 W = tw[j << (6 - s)];
      float2 x0 = sm[p0], x1 = sm[p1];
      float tr = W.x * x1.x - W.y * x1.y;
      float ti = W.x * x1.y + W.y * x1.x;
      sm[p0] = make_float2(x0.x + tr, x0.y + ti);
      sm[p1] = make_float2(x0.x - tr, x0.y - ti);
    }
    __syncthreads();
  }

  // fftshift + amp/phase, write bf16 features:
  // feats[b][c*2*HW + 0*HW + i] = amp, [... + 1*HW + i] = phase
  unsigned short* dst = feats + (size_t)b * IN_DIM + c * 32768;
  for (int i = tid; i < 16384; i += 256) {
    int h = i >> 7, w = i & 127;
    int sh = (h + 64) & 127, sw = (w + 64) & 127;
    float2 F = sm[(sh << 7) | sw];
    float amp = sqrtf(F.x * F.x + F.y * F.y);
    float ph = atan2f(F.y, F.x);
    dst[i] = f2bf(amp);
    dst[16384 + i] = f2bf(ph);
  }
}

// ---------------------------------------------------------------------------
// Kernel 2: layer-1 GEMM, split-K. C[256x512] = feats[256xK] * W1[512xK]^T
// Tile MT=256 (all rows), NT=64, K chunk 3072 (S=32). bf16 MFMA 16x16x32.
// W1 is fp32 in HBM, converted to bf16 while staging to LDS.
// Writes fp32 partials [32][256][512] (deterministic; no atomics).
// ---------------------------------------------------------------------------
__global__ __launch_bounds__(256) void gemm1_kernel(
    const unsigned short* __restrict__ feats, const float* __restrict__ W1,
    float* __restrict__ partial) {
  __shared__ __align__(16) unsigned short Asm[256 * 40];  // pitch 40 (pad 8)
  __shared__ __align__(16) unsigned short Bsm[64 * 40];
  const int tid = threadIdx.x;
  const int nt = blockIdx.x;  // 0..7
  const int ks = blockIdx.y;  // 0..31
  const int wv = tid >> 6, lane = tid & 63;
  const int n0 = nt * 64;
  const size_t k0 = (size_t)ks * 3072;

  f32x4 acc[4][4];
#pragma unroll
  for (int i = 0; i < 4; ++i)
#pragma unroll
    for (int j = 0; j < 4; ++j) acc[i][j] = (f32x4){0.f, 0.f, 0.f, 0.f};

  const int arow = tid >> 2;           // 0..63 (4 reps, +64 each)
  const int ak8 = (tid & 3) * 8;       // k offset in elems
  const int brow = tid >> 2;           // 0..63
  const int bk8 = (tid & 3) * 8;

  for (int kk = 0; kk < 96; ++kk) {
    size_t kb = k0 + (size_t)kk * 32;
    // issue global loads into regs first (hide latency across the barrier)
    u16x8 av[4];
#pragma unroll
    for (int r = 0; r < 4; ++r)
      av[r] = *reinterpret_cast<const u16x8*>(
          feats + (size_t)(arow + r * 64) * IN_DIM + kb + ak8);
    const float* wsrc = W1 + (size_t)(n0 + brow) * IN_DIM + kb + bk8;
    float4 f0 = *reinterpret_cast<const float4*>(wsrc);
    float4 f1 = *reinterpret_cast<const float4*>(wsrc + 4);
    __syncthreads();  // previous iteration's LDS reads complete
#pragma unroll
    for (int r = 0; r < 4; ++r)
      *reinterpret_cast<u16x8*>(&Asm[(arow + r * 64) * 40 + ak8]) = av[r];
    u16x8 bw;
    bw[0] = f2bf(f0.x); bw[1] = f2bf(f0.y); bw[2] = f2bf(f0.z); bw[3] = f2bf(f0.w);
    bw[4] = f2bf(f1.x); bw[5] = f2bf(f1.y); bw[6] = f2bf(f1.z); bw[7] = f2bf(f1.w);
    *reinterpret_cast<u16x8*>(&Bsm[brow * 40 + bk8]) = bw;
    __syncthreads();  // LDS tile ready

    const int rm = lane & 15, ko = (lane >> 4) * 8;
    bh8 a[4], bf[4];
#pragma unroll
    for (int i = 0; i < 4; ++i)
      a[i] = *reinterpret_cast<const bh8*>(&Asm[(wv * 64 + i * 16 + rm) * 40 + ko]);
#pragma unroll
    for (int j = 0; j < 4; ++j)
      bf[j] = *reinterpret_cast<const bh8*>(&Bsm[(j * 16 + rm) * 40 + ko]);
#pragma unroll
    for (int i = 0; i < 4; ++i)
#pragma unroll
      for (int j = 0; j < 4; ++j)
        acc[i][j] =
            __builtin_amdgcn_mfma_f32_16x16x32_bf16(a[i], bf[j], acc[i][j], 0, 0, 0);
  }

  // epilogue: C/D layout col=lane&15, row=(lane>>4)*4+reg (m89-verified)
  const int rm = lane & 15, rg = lane >> 4;
  float* pbase = partial + ((size_t)ks << 17);
#pragma unroll
  for (int i = 0; i < 4; ++i) {
#pragma unroll
    for (int j = 0; j < 4; ++j) {
      int n = n0 + j * 16 + rm;
#pragma unroll
      for (int r = 0; r < 4; ++r) {
        int m = wv * 64 + i * 16 + rg * 4 + r;
        pbase[((size_t)m << 9) + n] = acc[i][j][r];
      }
    }
  }
}

// ---------------------------------------------------------------------------
// Kernel 3: reduce split-K partials + bias + ReLU -> x1 [256][512] fp32
// ---------------------------------------------------------------------------
__global__ __launch_bounds__(256) void reduce1_kernel(
    const float* __restrict__ partial, const float* __restrict__ b1,
    float* __restrict__ x1) {
  int i = blockIdx.x * 256 + threadIdx.x;  // 0..131071
  float s = b1[i & 511];
#pragma unroll
  for (int p = 0; p < 32; ++p) s += partial[((size_t)p << 17) + i];
  x1[i] = fmaxf(s, 0.0f);
}

// ---------------------------------------------------------------------------
// Kernel 4: x2 = relu(x1 @ W2^T + b2). block = batch row, thread = out col.
// ---------------------------------------------------------------------------
__global__ __launch_bounds__(256) void fc2_kernel(
    const float* __restrict__ x1, const float* __restrict__ W2,
    const float* __restrict__ b2, float* __restrict__ x2) {
  __shared__ float xs[512];
  int b = blockIdx.x, n = threadIdx.x;
  xs[n] = x1[b * 512 + n];
  xs[n + 256] = x1[b * 512 + 256 + n];
  __syncthreads();
  float acc = b2[n];
  const float* wr = W2 + (size_t)n * 512;
#pragma unroll 4
  for (int k = 0; k < 512; k += 4) {
    float4 w = *reinterpret_cast<const float4*>(wr + k);
    acc += xs[k] * w.x + xs[k + 1] * w.y + xs[k + 2] * w.z + xs[k + 3] * w.w;
  }
  x2[b * 256 + n] = fmaxf(acc, 0.0f);
}

// ---------------------------------------------------------------------------
// Kernel 5: out = x2 @ W3^T + b3 (no ReLU)
// ---------------------------------------------------------------------------
__global__ __launch_bounds__(128) void fc3_kernel(
    const float* __restrict__ x2, const float* __restrict__ W3,
    const float* __restrict__ b3, float* __restrict__ out) {
  __shared__ float xs[256];
  int b = blockIdx.x, n = threadIdx.x;
  xs[n] = x2[b * 256 + n];
  xs[n + 128] = x2[b * 256 + 128 + n];
  __syncthreads();
  float acc = b3[n];
  const float* wr = W3 + (size_t)n * 256;
#pragma unroll 4
  for (int k = 0; k < 256; k += 4) {
    float4 w = *reinterpret_cast<const float4*>(wr + k);
    acc += xs[k] * w.x + xs[k + 1] * w.y + xs[k + 2] * w.z + xs[k + 3] * w.w;
  }
  out[b * 128 + n] = acc;
}

extern "C" void kernel_launch(void* const* d_in, const int* in_sizes, int n_in,
                              void* d_out, int out_size, void* d_ws, size_t ws_size,
                              hipStream_t stream) {
  const float* img = (const float*)d_in[0];
  const float* W1 = (const float*)d_in[1];
  const float* b1 = (const float*)d_in[2];
  const float* W2 = (const float*)d_in[3];
  const float* b2 = (const float*)d_in[4];
  const float* W3 = (const float*)d_in[5];
  const float* b3 = (const float*)d_in[6];
  float* out = (float*)d_out;
  char* ws = (char*)d_ws;

  // ws layout:
  //   feats   bf16 [256][98304]      @ 0          (50,331,648 B)
  //   partial fp32 [32][256][512]    @ 50331648   (16,777,216 B)
  //   x1      fp32 [256][512]        @ 67108864   (524,288 B)
  //   x2      fp32 [256][256]        @ 67633152   (262,144 B)
  unsigned short* feats = (unsigned short*)ws;
  float* partial = (float*)(ws + 50331648);
  float* x1 = (float*)(ws + 67108864);
  float* x2 = (float*)(ws + 67633152);

  hipLaunchKernelGGL(fft_feats_kernel, dim3(3, 256), dim3(256), 0, stream, img, feats);
  hipLaunchKernelGGL(gemm1_kernel, dim3(8, 32), dim3(256), 0, stream, feats, W1, partial);
  hipLaunchKernelGGL(reduce1_kernel, dim3(512), dim3(256), 0, stream, partial, b1, x1);
  hipLaunchKernelGGL(fc2_kernel, dim3(256), dim3(256), 0, stream, x1, W2, b2, x2);
  hipLaunchKernelGGL(fc3_kernel, dim3(256), dim3(128), 0, stream, x2, W3, b3, out);
}

// Round 2
// 221.952 us; speedup vs baseline: 1.5458x; 1.5458x over previous
//
#include <hip/hip_runtime.h>
#include <hip/hip_bf16.h>

#define IN_DIM 98304

typedef short bh8 __attribute__((ext_vector_type(8)));
typedef float f32x4 __attribute__((ext_vector_type(4)));
typedef unsigned short u16x8 __attribute__((ext_vector_type(8)));

__device__ __forceinline__ unsigned short f2bf(float f) {
  __hip_bfloat16 h = __float2bfloat16(f);
  return __builtin_bit_cast(unsigned short, h);
}

__device__ __forceinline__ void bfly(float2& a, float2& b, float wr, float wi) {
  float tr = wr * b.x - wi * b.y;
  float ti = wr * b.y + wi * b.x;
  b.x = a.x - tr; b.y = a.y - ti;
  a.x += tr; a.y += ti;
}

__device__ __forceinline__ float2 cmul(float2 a, float2 w) {
  return make_float2(a.x * w.x - a.y * w.y, a.x * w.y + a.y * w.x);
}

// 16-point FFT, input bit-reversed in v[], output natural order.
__device__ __forceinline__ void fft16(float2* v) {
  const float C8 = 0.70710678118654752f;
  const float C161 = 0.92387953251128674f, S161 = 0.38268343236508977f;
#pragma unroll
  for (int i = 0; i < 16; i += 2) bfly(v[i], v[i + 1], 1.f, 0.f);
#pragma unroll
  for (int i = 0; i < 16; i += 4) {
    bfly(v[i], v[i + 2], 1.f, 0.f);
    bfly(v[i + 1], v[i + 3], 0.f, -1.f);
  }
  {
    const float w8r[4] = {1.f, C8, 0.f, -C8};
    const float w8i[4] = {0.f, -C8, -1.f, -C8};
#pragma unroll
    for (int i = 0; i < 16; i += 8) {
#pragma unroll
      for (int j = 0; j < 4; ++j) bfly(v[i + j], v[i + j + 4], w8r[j], w8i[j]);
    }
  }
  {
    const float w16r[8] = {1.f, C161, C8, S161, 0.f, -S161, -C8, -C161};
    const float w16i[8] = {0.f, -S161, -C8, -C161, -1.f, -C161, -C8, -S161};
#pragma unroll
    for (int j = 0; j < 8; ++j) bfly(v[j], v[j + 8], w16r[j], w16i[j]);
  }
}

// 8-point FFT, input bit-reversed in v[], output natural order.
__device__ __forceinline__ void fft8(float2* v) {
  const float C8 = 0.70710678118654752f;
#pragma unroll
  for (int i = 0; i < 8; i += 2) bfly(v[i], v[i + 1], 1.f, 0.f);
#pragma unroll
  for (int i = 0; i < 8; i += 4) {
    bfly(v[i], v[i + 2], 1.f, 0.f);
    bfly(v[i + 1], v[i + 3], 0.f, -1.f);
  }
  bfly(v[0], v[4], 1.f, 0.f);
  bfly(v[1], v[5], C8, -C8);
  bfly(v[2], v[6], 0.f, -1.f);
  bfly(v[3], v[7], -C8, -C8);
}

// swizzled LDS index (float2 units): XOR row low bits into column bits 1..3.
// keeps bit0 (so adjacent float2 pairs / float4 writes stay aligned), spreads
// stride-128 row accesses across banks (32-way -> 4-way).
__device__ __forceinline__ int IDX(int r, int cc) {
  return (r << 7) + (cc ^ ((r & 7) << 1));
}

// ---------------------------------------------------------------------------
// Kernel 1: per-(image,channel) 128x128 FFT2 + fftshift + amp/phase -> bf16.
// One block (512 thr) per (c,b). 128 = 16x8 two-stage register FFT:
//   stage1: 16-pt FFT in regs over n1 (x[8*n1+n2]) + W128^{n2*k1} twiddle
//   stage2: 8-pt FFT in regs over n2  -> X[k1+16*k2]
// 2 LDS round trips per dimension instead of 7.
// ---------------------------------------------------------------------------
__global__ __launch_bounds__(512) void fft_feats_kernel(
    const float* __restrict__ img, unsigned short* __restrict__ feats) {
  __shared__ float2 sm[16384];
  __shared__ float2 tw[128];
  const int tid = threadIdx.x;
  const int c = blockIdx.x, b = blockIdx.y;
  const float* src = img + ((size_t)(b * 3 + c) << 14);

  static const int BR4[16] = {0, 8, 4, 12, 2, 10, 6, 14, 1, 9, 5, 13, 3, 11, 7, 15};
  static const int BR3[8] = {0, 4, 2, 6, 1, 5, 3, 7};

  if (tid < 128) {
    float sv, cv;
    sincosf(-6.28318530717958647692f * (float)tid / 128.0f, &sv, &cv);
    tw[tid] = make_float2(cv, sv);
  }
  // load 128x128 reals, coalesced float4, as (re,0) complex
  for (int i4 = tid; i4 < 4096; i4 += 512) {
    float4 x = *reinterpret_cast<const float4*>(src + (i4 << 2));
    int r = i4 >> 5, cc = (i4 << 2) & 127;
    *reinterpret_cast<float4*>(&sm[IDX(r, cc)]) = make_float4(x.x, 0.f, x.y, 0.f);
    *reinterpret_cast<float4*>(&sm[IDX(r, cc + 2)]) = make_float4(x.z, 0.f, x.w, 0.f);
  }
  __syncthreads();

  // ---- row pass, stage 1: thread slot (r, n2) owns cols == n2 (mod 8)
#pragma unroll
  for (int it = 0; it < 2; ++it) {
    int ss = it * 512 + tid;
    int r = ss >> 3, n2 = ss & 7;
    float2 v[16];
#pragma unroll
    for (int j = 0; j < 16; ++j) v[j] = sm[IDX(r, (BR4[j] << 3) + n2)];
    fft16(v);
#pragma unroll
    for (int k1 = 1; k1 < 16; ++k1) v[k1] = cmul(v[k1], tw[n2 * k1]);
#pragma unroll
    for (int k1 = 0; k1 < 16; ++k1) sm[IDX(r, (k1 << 3) + n2)] = v[k1];
  }
  __syncthreads();

  // ---- row pass, stage 2: slot (r, t8) handles k1 = t8, t8+8
#pragma unroll
  for (int it = 0; it < 2; ++it) {
    int ss = it * 512 + tid;
    int r = ss >> 3, t8 = ss & 7;
    float2 u0[8], u1[8];
#pragma unroll
    for (int j = 0; j < 8; ++j) {
      u0[j] = sm[IDX(r, (t8 << 3) + BR3[j])];
      u1[j] = sm[IDX(r, ((t8 + 8) << 3) + BR3[j])];
    }
    __syncthreads();  // all reads of this row-group before any writes to it
    fft8(u0);
    fft8(u1);
#pragma unroll
    for (int k2 = 0; k2 < 8; ++k2) {
      sm[IDX(r, t8 + (k2 << 4))] = u0[k2];
      sm[IDX(r, t8 + 8 + (k2 << 4))] = u1[k2];
    }
  }
  __syncthreads();

  // ---- col pass, stage 1: slot (col, n2) owns rows == n2 (mod 8)
#pragma unroll
  for (int it = 0; it < 2; ++it) {
    int ss = it * 512 + tid;
    int col = ss & 127, n2 = ss >> 7;
    float2 v[16];
#pragma unroll
    for (int j = 0; j < 16; ++j) v[j] = sm[IDX((BR4[j] << 3) + n2, col)];
    fft16(v);
#pragma unroll
    for (int k1 = 1; k1 < 16; ++k1) v[k1] = cmul(v[k1], tw[n2 * k1]);
#pragma unroll
    for (int k1 = 0; k1 < 16; ++k1) sm[IDX((k1 << 3) + n2, col)] = v[k1];
  }
  __syncthreads();

  // ---- col pass, stage 2 + fftshift + amp/phase + global write
  unsigned short* dst = feats + (size_t)b * IN_DIM + c * 32768;
#pragma unroll
  for (int it = 0; it < 2; ++it) {
    int ss = it * 512 + tid;
    int col = ss & 127, t8 = ss >> 7;
    float2 u0[8], u1[8];
#pragma unroll
    for (int j = 0; j < 8; ++j) {
      u0[j] = sm[IDX((t8 << 3) + BR3[j], col)];
      u1[j] = sm[IDX(((t8 + 8) << 3) + BR3[j], col)];
    }
    fft8(u0);
    fft8(u1);
    int ow = col ^ 64;
#pragma unroll
    for (int k2 = 0; k2 < 8; ++k2) {
      int oh0 = (t8 + (k2 << 4)) ^ 64;
      int oh1 = (t8 + 8 + (k2 << 4)) ^ 64;
      float a0 = sqrtf(u0[k2].x * u0[k2].x + u0[k2].y * u0[k2].y);
      float p0 = atan2f(u0[k2].y, u0[k2].x);
      float a1 = sqrtf(u1[k2].x * u1[k2].x + u1[k2].y * u1[k2].y);
      float p1 = atan2f(u1[k2].y, u1[k2].x);
      dst[(oh0 << 7) + ow] = f2bf(a0);
      dst[16384 + (oh0 << 7) + ow] = f2bf(p0);
      dst[(oh1 << 7) + ow] = f2bf(a1);
      dst[16384 + (oh1 << 7) + ow] = f2bf(p1);
    }
  }
}

// ---------------------------------------------------------------------------
// Kernel 2: layer-1 GEMM, split-K, software-pipelined.
// C[256x512] = feats[256xK](bf16) * W1[512xK]^T(fp32->bf16 on the fly)
// grid (8, S): NT=64 cols, K chunk = IN_DIM/S. Prefetch next iter's global
// loads into regs BEFORE the MFMA cluster so HBM latency hides under compute.
// ---------------------------------------------------------------------------
__global__ __launch_bounds__(256, 2) void gemm1_kernel(
    const unsigned short* __restrict__ feats, const float* __restrict__ W1,
    float* __restrict__ partial, int kchunk) {
  __shared__ __align__(16) unsigned short Asm[256 * 40];  // pitch 40 (pad 8)
  __shared__ __align__(16) unsigned short Bsm[64 * 40];
  const int tid = threadIdx.x;
  const int nt = blockIdx.x;
  const int ks = blockIdx.y;
  const int wv = tid >> 6, lane = tid & 63;
  const int n0 = nt * 64;
  const size_t k0 = (size_t)ks * kchunk;
  const int iters = kchunk >> 5;

  f32x4 acc[4][4];
#pragma unroll
  for (int i = 0; i < 4; ++i)
#pragma unroll
    for (int j = 0; j < 4; ++j) acc[i][j] = (f32x4){0.f, 0.f, 0.f, 0.f};

  const int arow = tid >> 2;      // 0..63
  const int ak8 = (tid & 3) * 8;  // k offset in elems

  u16x8 av[4];
  float4 f0, f1;
  {  // prefetch iteration 0
#pragma unroll
    for (int r = 0; r < 4; ++r)
      av[r] = *reinterpret_cast<const u16x8*>(
          feats + (size_t)(arow + r * 64) * IN_DIM + k0 + ak8);
    const float* wsrc = W1 + (size_t)(n0 + arow) * IN_DIM + k0 + ak8;
    f0 = *reinterpret_cast<const float4*>(wsrc);
    f1 = *reinterpret_cast<const float4*>(wsrc + 4);
  }

  for (int kk = 0; kk < iters; ++kk) {
    __syncthreads();  // previous iteration's LDS frag reads complete
#pragma unroll
    for (int r = 0; r < 4; ++r)
      *reinterpret_cast<u16x8*>(&Asm[(arow + r * 64) * 40 + ak8]) = av[r];
    u16x8 bw;
    bw[0] = f2bf(f0.x); bw[1] = f2bf(f0.y); bw[2] = f2bf(f0.z); bw[3] = f2bf(f0.w);
    bw[4] = f2bf(f1.x); bw[5] = f2bf(f1.y); bw[6] = f2bf(f1.z); bw[7] = f2bf(f1.w);
    *reinterpret_cast<u16x8*>(&Bsm[arow * 40 + ak8]) = bw;
    __syncthreads();  // tile ready

    if (kk + 1 < iters) {  // prefetch next tile; overlaps MFMA below
      size_t kb = k0 + (size_t)(kk + 1) * 32;
#pragma unroll
      for (int r = 0; r < 4; ++r)
        av[r] = *reinterpret_cast<const u16x8*>(
            feats + (size_t)(arow + r * 64) * IN_DIM + kb + ak8);
      const float* wsrc = W1 + (size_t)(n0 + arow) * IN_DIM + kb + ak8;
      f0 = *reinterpret_cast<const float4*>(wsrc);
      f1 = *reinterpret_cast<const float4*>(wsrc + 4);
    }

    const int rm = lane & 15, ko = (lane >> 4) * 8;
    bh8 a[4], bf[4];
#pragma unroll
    for (int i = 0; i < 4; ++i)
      a[i] = *reinterpret_cast<const bh8*>(&Asm[(wv * 64 + i * 16 + rm) * 40 + ko]);
#pragma unroll
    for (int j = 0; j < 4; ++j)
      bf[j] = *reinterpret_cast<const bh8*>(&Bsm[(j * 16 + rm) * 40 + ko]);
#pragma unroll
    for (int i = 0; i < 4; ++i)
#pragma unroll
      for (int j = 0; j < 4; ++j)
        acc[i][j] =
            __builtin_amdgcn_mfma_f32_16x16x32_bf16(a[i], bf[j], acc[i][j], 0, 0, 0);
  }

  // epilogue: C/D layout col=lane&15, row=(lane>>4)*4+reg (m89-verified)
  const int rm = lane & 15, rg = lane >> 4;
  float* pbase = partial + ((size_t)ks << 17);
#pragma unroll
  for (int i = 0; i < 4; ++i) {
#pragma unroll
    for (int j = 0; j < 4; ++j) {
      int n = n0 + j * 16 + rm;
#pragma unroll
      for (int r = 0; r < 4; ++r) {
        int m = wv * 64 + i * 16 + rg * 4 + r;
        pbase[((size_t)m << 9) + n] = acc[i][j][r];
      }
    }
  }
}

// ---------------------------------------------------------------------------
// Kernel 3: reduce split-K partials + bias + ReLU -> x1 [256][512] fp32
// ---------------------------------------------------------------------------
__global__ __launch_bounds__(256) void reduce1_kernel(
    const float* __restrict__ partial, const float* __restrict__ b1,
    float* __restrict__ x1, int S) {
  int i = blockIdx.x * 256 + threadIdx.x;  // 0..131071
  float s = b1[i & 511];
  for (int p = 0; p < S; ++p) s += partial[((size_t)p << 17) + i];
  x1[i] = fmaxf(s, 0.0f);
}

// ---------------------------------------------------------------------------
// Kernel 4: x2 = relu(x1 @ W2^T + b2)
// ---------------------------------------------------------------------------
__global__ __launch_bounds__(256) void fc2_kernel(
    const float* __restrict__ x1, const float* __restrict__ W2,
    const float* __restrict__ b2, float* __restrict__ x2) {
  __shared__ float xs[512];
  int b = blockIdx.x, n = threadIdx.x;
  xs[n] = x1[b * 512 + n];
  xs[n + 256] = x1[b * 512 + 256 + n];
  __syncthreads();
  float acc = b2[n];
  const float* wr = W2 + (size_t)n * 512;
#pragma unroll 4
  for (int k = 0; k < 512; k += 4) {
    float4 w = *reinterpret_cast<const float4*>(wr + k);
    acc += xs[k] * w.x + xs[k + 1] * w.y + xs[k + 2] * w.z + xs[k + 3] * w.w;
  }
  x2[b * 256 + n] = fmaxf(acc, 0.0f);
}

// ---------------------------------------------------------------------------
// Kernel 5: out = x2 @ W3^T + b3
// ---------------------------------------------------------------------------
__global__ __launch_bounds__(128) void fc3_kernel(
    const float* __restrict__ x2, const float* __restrict__ W3,
    const float* __restrict__ b3, float* __restrict__ out) {
  __shared__ float xs[256];
  int b = blockIdx.x, n = threadIdx.x;
  xs[n] = x2[b * 256 + n];
  xs[n + 128] = x2[b * 256 + 128 + n];
  __syncthreads();
  float acc = b3[n];
  const float* wr = W3 + (size_t)n * 256;
#pragma unroll 4
  for (int k = 0; k < 256; k += 4) {
    float4 w = *reinterpret_cast<const float4*>(wr + k);
    acc += xs[k] * w.x + xs[k + 1] * w.y + xs[k + 2] * w.z + xs[k + 3] * w.w;
  }
  out[b * 128 + n] = acc;
}

extern "C" void kernel_launch(void* const* d_in, const int* in_sizes, int n_in,
                              void* d_out, int out_size, void* d_ws, size_t ws_size,
                              hipStream_t stream) {
  const float* img = (const float*)d_in[0];
  const float* W1 = (const float*)d_in[1];
  const float* b1 = (const float*)d_in[2];
  const float* W2 = (const float*)d_in[3];
  const float* b2 = (const float*)d_in[4];
  const float* W3 = (const float*)d_in[5];
  const float* b3 = (const float*)d_in[6];
  float* out = (float*)d_out;
  char* ws = (char*)d_ws;

  // ws layout:
  //   feats   bf16 [256][98304]    @ 0          (50,331,648 B)
  //   partial fp32 [S][256][512]   @ 50331648   (S * 524,288 B)
  //   x1      fp32 [256][512]
  //   x2      fp32 [256][256]
  const size_t need64 = 50331648ull + 64ull * 524288 + 524288 + 262144;
  const int S = (ws_size >= need64) ? 64 : 32;  // deterministic per ws_size
  const int kchunk = IN_DIM / S;

  unsigned short* feats = (unsigned short*)ws;
  float* partial = (float*)(ws + 50331648);
  float* x1 = (float*)(ws + 50331648 + (size_t)S * 524288);
  float* x2 = x1 + 131072;

  hipLaunchKernelGGL(fft_feats_kernel, dim3(3, 256), dim3(512), 0, stream, img, feats);
  hipLaunchKernelGGL(gemm1_kernel, dim3(8, S), dim3(256), 0, stream, feats, W1, partial, kchunk);
  hipLaunchKernelGGL(reduce1_kernel, dim3(512), dim3(256), 0, stream, partial, b1, x1, S);
  hipLaunchKernelGGL(fc2_kernel, dim3(256), dim3(256), 0, stream, x1, W2, b2, x2);
  hipLaunchKernelGGL(fc3_kernel, dim3(256), dim3(128), 0, stream, x2, W3, b3, out);
}